// Round 1
// baseline (10293.716 us; speedup 1.0000x reference)
//
#include <hip/hip_runtime.h>
#include <hip/hip_bf16.h>

// ---------------------------------------------------------------------------
// LSTMCell scan, T=4096, HID=2048, input=2048 (src||dst), fp32 in/out.
// Strategy:
//   K1 init_tags : reset tagged h-broadcast buffers (stream-ordered => global sync)
//   K2 xg_gemm   : xg[t][j] = (x @ W_ih^T + b_ih + b_hh), fp16 MFMA, stored fp16 in ws
//   K3 lstm_scan : persistent 256-WG kernel; W_hh fp16 in VGPRs (128 regs/lane);
//                  per step: poll tagged h pairs -> LDS -> v_dot2_f32_f16 GEMV ->
//                  LDS reduce -> gates -> publish h_{t+1} as {tag,half2} 8B atomics.
// ---------------------------------------------------------------------------

#define T_STEPS 4096
#define FOURH   8192

typedef _Float16 f16;
typedef _Float16 f16x2 __attribute__((ext_vector_type(2)));
typedef _Float16 f16x8 __attribute__((ext_vector_type(8)));
typedef float    f32x4 __attribute__((ext_vector_type(4)));

#if __has_builtin(__builtin_amdgcn_fdot2)
#define FDOT2(a, b, c) __builtin_amdgcn_fdot2((a), (b), (c), false)
#else
#define FDOT2(a, b, c) ((c) + (float)(a)[0] * (float)(b)[0] + (float)(a)[1] * (float)(b)[1])
#endif

// ---------------------------------------------------------------------------
// K1: reset the tagged h buffers. Buffer0 holds h_0 = 0 with tag 1; buffer1 tag 0.
__global__ void init_tags(unsigned long long* __restrict__ hbuf) {
    int i = blockIdx.x * 256 + threadIdx.x;
    if (i < 2048) hbuf[i] = (i < 1024) ? (1ULL << 32) : 0ULL;
}

// ---------------------------------------------------------------------------
// K2: xg = concat(src,dst) @ W_ih^T + (b_ih + b_hh), fp16 output.
// 128x128 tile, BK=32, 4 waves (2x2), 16x16x32 f16 MFMA, fused f32->f16 staging.
#define GBM 128
#define GBN 128
#define GBK 32
#define LDT 40   // halfs per LDS row (32 + 8 pad, keeps 16B alignment, ~2-way banks)

__global__ __launch_bounds__(256) void xg_gemm(
    const float* __restrict__ src, const float* __restrict__ dst,
    const float* __restrict__ Wih, const float* __restrict__ bi,
    const float* __restrict__ bh, f16* __restrict__ xg) {
    __shared__ __align__(16) f16 As[GBM * LDT];
    __shared__ __align__(16) f16 Bs[GBN * LDT];

    const int tid = threadIdx.x;
    const int bx  = blockIdx.x;
    const int tm  = bx >> 6, tn = bx & 63;
    const int m0  = tm * GBM, n0 = tn * GBN;
    const int lane = tid & 63, wv = tid >> 6;
    const int wm = (wv >> 1) * 64, wn = (wv & 1) * 64;
    const int fr = lane & 15, kg = lane >> 4;

    const int srow = tid >> 1;          // 0..127
    const int sk   = (tid & 1) * 16;    // 0 or 16

    f32x4 acc[4][4];
#pragma unroll
    for (int i = 0; i < 4; ++i)
#pragma unroll
        for (int j = 0; j < 4; ++j) acc[i][j] = (f32x4){0.f, 0.f, 0.f, 0.f};

    for (int kt = 0; kt < 2048 / GBK; ++kt) {
        const int gk = kt * GBK + sk;
        // ---- stage A (x = src||dst along k) ----
        {
            const float* ap = (gk < 1024) ? (src + (size_t)(m0 + srow) * 1024 + gk)
                                          : (dst + (size_t)(m0 + srow) * 1024 + (gk - 1024));
            float4 fa = *(const float4*)(ap + 0);
            float4 fb = *(const float4*)(ap + 4);
            float4 fc = *(const float4*)(ap + 8);
            float4 fd = *(const float4*)(ap + 12);
            f16x8 lo, hi;
            lo[0] = (f16)fa.x; lo[1] = (f16)fa.y; lo[2] = (f16)fa.z; lo[3] = (f16)fa.w;
            lo[4] = (f16)fb.x; lo[5] = (f16)fb.y; lo[6] = (f16)fb.z; lo[7] = (f16)fb.w;
            hi[0] = (f16)fc.x; hi[1] = (f16)fc.y; hi[2] = (f16)fc.z; hi[3] = (f16)fc.w;
            hi[4] = (f16)fd.x; hi[5] = (f16)fd.y; hi[6] = (f16)fd.z; hi[7] = (f16)fd.w;
            *(f16x8*)&As[srow * LDT + sk]     = lo;
            *(f16x8*)&As[srow * LDT + sk + 8] = hi;
        }
        // ---- stage B (W_ih rows) ----
        {
            const float* bp = Wih + (size_t)(n0 + srow) * 2048 + gk;
            float4 fa = *(const float4*)(bp + 0);
            float4 fb = *(const float4*)(bp + 4);
            float4 fc = *(const float4*)(bp + 8);
            float4 fd = *(const float4*)(bp + 12);
            f16x8 lo, hi;
            lo[0] = (f16)fa.x; lo[1] = (f16)fa.y; lo[2] = (f16)fa.z; lo[3] = (f16)fa.w;
            lo[4] = (f16)fb.x; lo[5] = (f16)fb.y; lo[6] = (f16)fb.z; lo[7] = (f16)fb.w;
            hi[0] = (f16)fc.x; hi[1] = (f16)fc.y; hi[2] = (f16)fc.z; hi[3] = (f16)fc.w;
            hi[4] = (f16)fd.x; hi[5] = (f16)fd.y; hi[6] = (f16)fd.z; hi[7] = (f16)fd.w;
            *(f16x8*)&Bs[srow * LDT + sk]     = lo;
            *(f16x8*)&Bs[srow * LDT + sk + 8] = hi;
        }
        __syncthreads();
        f16x8 a[4], b[4];
#pragma unroll
        for (int m = 0; m < 4; ++m) a[m] = *(const f16x8*)&As[(wm + m * 16 + fr) * LDT + kg * 8];
#pragma unroll
        for (int n = 0; n < 4; ++n) b[n] = *(const f16x8*)&Bs[(wn + n * 16 + fr) * LDT + kg * 8];
#pragma unroll
        for (int m = 0; m < 4; ++m)
#pragma unroll
            for (int n = 0; n < 4; ++n)
                acc[m][n] = __builtin_amdgcn_mfma_f32_16x16x32_f16(a[m], b[n], acc[m][n], 0, 0, 0);
        __syncthreads();
    }
    // ---- epilogue: + bias, f16 store. C/D: col=lane&15, row=(lane>>4)*4+reg ----
#pragma unroll
    for (int n = 0; n < 4; ++n) {
        const int col = n0 + wn + n * 16 + fr;
        const float bias = bi[col] + bh[col];
#pragma unroll
        for (int m = 0; m < 4; ++m) {
            const int rb = m0 + wm + m * 16 + kg * 4;
#pragma unroll
            for (int r = 0; r < 4; ++r)
                xg[(size_t)(rb + r) * FOURH + col] = (f16)(acc[m][n][r] + bias);
        }
    }
}

// ---------------------------------------------------------------------------
// K3: persistent scan. 256 WGs x 256 threads. WG w owns m in [8w,8w+8) across all
// 4 gates (rows gt*2048 + 8w + r). Wave gt handles gate gt (8 rows).
// Per lane: k-pairs p = lane + 64*j (j=0..15) -> weights in 128 VGPRs (f16x2).
__global__ __launch_bounds__(256, 1) void lstm_scan(
    const float* __restrict__ Whh, const f16* __restrict__ xg,
    unsigned long long* __restrict__ hbuf, float* __restrict__ out) {
    const int w    = blockIdx.x;    // 0..255
    const int tid  = threadIdx.x;
    const int lane = tid & 63;
    const int gt   = tid >> 6;      // wave id == gate id
    const int m0   = w * 8;

    __shared__ unsigned h2s[1024];          // packed half2 h pairs
    __shared__ float scratch[4][8][68];     // per-wave reduce scratch (padded)
    __shared__ float gatebuf[4][8];         // [gate][m] pre-activations

    // ---- load weights into registers (fp16 pairs) ----
    f16x2 wreg[8][16];
#pragma unroll
    for (int r = 0; r < 8; ++r) {
        const float* wrow = Whh + (size_t)(gt * 2048 + m0 + r) * 2048;
#pragma unroll
        for (int j = 0; j < 16; ++j) {
            const int p = lane + 64 * j;
            float2 f = *(const float2*)(wrow + 2 * p);
            f16x2 v; v[0] = (f16)f.x; v[1] = (f16)f.y;
            wreg[r][j] = v;
        }
    }

    unsigned long long* base0 = hbuf;
    unsigned long long* base1 = hbuf + 1024;
    float c_st = 0.f;                       // cell state (wave0 lanes 0..7)
    const int p0 = gt * 256 + lane;         // this wave's poll quarter

    for (int t = 0; t < T_STEPS; ++t) {
        // prefetch xg for this step's writing lanes (r = lane>>3)
        float xgv = 0.f;
        if ((lane & 7) == 0)
            xgv = (float)xg[(size_t)t * FOURH + gt * 2048 + m0 + (lane >> 3)];

        unsigned long long* cur = (t & 1) ? base1 : base0;
        const unsigned tagw = (unsigned)(t + 1);
        unsigned long long v0, v1, v2, v3;
        for (;;) {
            v0 = __hip_atomic_load(cur + p0,       __ATOMIC_RELAXED, __HIP_MEMORY_SCOPE_AGENT);
            v1 = __hip_atomic_load(cur + p0 + 64,  __ATOMIC_RELAXED, __HIP_MEMORY_SCOPE_AGENT);
            v2 = __hip_atomic_load(cur + p0 + 128, __ATOMIC_RELAXED, __HIP_MEMORY_SCOPE_AGENT);
            v3 = __hip_atomic_load(cur + p0 + 192, __ATOMIC_RELAXED, __HIP_MEMORY_SCOPE_AGENT);
            if ((unsigned)(v0 >> 32) >= tagw && (unsigned)(v1 >> 32) >= tagw &&
                (unsigned)(v2 >> 32) >= tagw && (unsigned)(v3 >> 32) >= tagw)
                break;
            __builtin_amdgcn_s_sleep(1);
        }
        h2s[p0]       = (unsigned)v0;
        h2s[p0 + 64]  = (unsigned)v1;
        h2s[p0 + 128] = (unsigned)v2;
        h2s[p0 + 192] = (unsigned)v3;
        __syncthreads();   // barrier A: h2s complete (also fences vs prev-step reuse)

        // ---- GEMV partials: 8 rows x 16 dot2 from registers ----
        f16x2 hreg[16];
#pragma unroll
        for (int j = 0; j < 16; ++j)
            hreg[j] = __builtin_bit_cast(f16x2, h2s[lane + 64 * j]);
        float accv[8];
#pragma unroll
        for (int r = 0; r < 8; ++r) {
            float a = 0.f;
#pragma unroll
            for (int j = 0; j < 16; ++j) a = FDOT2(wreg[r][j], hreg[j], a);
            accv[r] = a;
        }
        // ---- reduce across 64 lanes per row ----
#pragma unroll
        for (int r = 0; r < 8; ++r) scratch[gt][r][lane] = accv[r];
        __syncthreads();   // barrier A2: scratch ready
        {
            const int r = lane >> 3, cc = lane & 7;
            const float* s = &scratch[gt][r][cc * 8];
            float s0 = s[0] + s[1] + s[2] + s[3] + s[4] + s[5] + s[6] + s[7];
            s0 += __shfl_xor(s0, 1);
            s0 += __shfl_xor(s0, 2);
            s0 += __shfl_xor(s0, 4);
            if (cc == 0) gatebuf[gt][r] = s0 + xgv;
        }
        __syncthreads();   // barrier B: gatebuf ready; protects h2s/scratch reuse

        // ---- gates + publish (wave 0) ----
        if (gt == 0) {
            float hval = 0.f;
            if (lane < 8) {
                const int m = lane;
                float gi = gatebuf[0][m], gf = gatebuf[1][m];
                float gg = gatebuf[2][m], go = gatebuf[3][m];
                float ig = 1.f / (1.f + __expf(-gi));
                float fg = 1.f / (1.f + __expf(-gf));
                float g  = 1.f - 2.f / (__expf(2.f * gg) + 1.f);
                float og = 1.f / (1.f + __expf(-go));
                float c  = fg * c_st + ig * g;
                c_st = c;
                hval = og * (1.f - 2.f / (__expf(2.f * c) + 1.f));
                if (t == T_STEPS - 1) out[m0 + m] = hval;
            }
            if (t != T_STEPS - 1) {
                float hlo = __shfl(hval, 2 * (lane & 3));
                float hhi = __shfl(hval, 2 * (lane & 3) + 1);
                if (lane < 4) {
                    f16x2 hp; hp[0] = (f16)hlo; hp[1] = (f16)hhi;
                    unsigned long long val = ((unsigned long long)(unsigned)(t + 2) << 32) |
                                             (unsigned long long)__builtin_bit_cast(unsigned, hp);
                    unsigned long long* nxt = (t & 1) ? base0 : base1;
                    __hip_atomic_store(nxt + w * 4 + lane, val,
                                       __ATOMIC_RELAXED, __HIP_MEMORY_SCOPE_AGENT);
                }
            }
        }
    }
}

// ---------------------------------------------------------------------------
extern "C" void kernel_launch(void* const* d_in, const int* in_sizes, int n_in,
                              void* d_out, int out_size, void* d_ws, size_t ws_size,
                              hipStream_t stream) {
    const float* src = (const float*)d_in[0];
    const float* dst = (const float*)d_in[1];
    const float* Wih = (const float*)d_in[2];
    const float* Whh = (const float*)d_in[3];
    const float* bi  = (const float*)d_in[4];
    const float* bh  = (const float*)d_in[5];
    float* out = (float*)d_out;

    // ws layout: [0, 64MB) xg fp16 (4096*8192); [64MB, +16KB) tagged h buffers.
    f16* xg = (f16*)d_ws;
    unsigned long long* hbuf =
        (unsigned long long*)((char*)d_ws + ((size_t)64 << 20));

    hipLaunchKernelGGL(init_tags, dim3(8), dim3(256), 0, stream, hbuf);
    hipLaunchKernelGGL(xg_gemm, dim3((4096 / GBM) * (FOURH / GBN)), dim3(256), 0, stream,
                       src, dst, Wih, bi, bh, xg);
    hipLaunchKernelGGL(lstm_scan, dim3(256), dim3(256), 0, stream, Whh, xg, hbuf, out);
}

// Round 2
// 8956.812 us; speedup vs baseline: 1.1493x; 1.1493x over previous
//
#include <hip/hip_runtime.h>
#include <hip/hip_bf16.h>

// ---------------------------------------------------------------------------
// LSTMCell scan, T=4096, HID=2048, input=2048 (src||dst), fp32 in/out.
//   K1 init_tags : reset tagged h-broadcast buffers
//   K2 xg_gemm   : xg = x @ W_ih^T + (b_ih+b_hh), fp16 MFMA -> ws
//   K3 lstm_scan : persistent 256-WG kernel. W_hh fp16 PINNED in VGPRs
//                  (asm liveness barrier). Per step: each wave polls its own
//                  k-quarter of tagged {tag,h2} entries -> dot from regs ->
//                  swizzled LDS partials -> ONE barrier -> 8-lane reduce ->
//                  in-wave gate gather -> publish one pair per wave.
// ---------------------------------------------------------------------------

#define T_STEPS 4096
#define FOURH   8192

typedef _Float16 f16;
typedef _Float16 f16x2 __attribute__((ext_vector_type(2)));
typedef _Float16 f16x8 __attribute__((ext_vector_type(8)));
typedef float    f32x4 __attribute__((ext_vector_type(4)));

#if __has_builtin(__builtin_amdgcn_fdot2)
#define FDOT2(a, b, c) __builtin_amdgcn_fdot2((a), (b), (c), false)
#else
#define FDOT2(a, b, c) ((c) + (float)(a)[0] * (float)(b)[0] + (float)(a)[1] * (float)(b)[1])
#endif

// ---------------------------------------------------------------------------
// K1: buffer0 holds h_0 = 0 with tag 1; buffer1 tag 0.
__global__ void init_tags(unsigned long long* __restrict__ hbuf) {
    int i = blockIdx.x * 256 + threadIdx.x;
    if (i < 2048) hbuf[i] = (i < 1024) ? (1ULL << 32) : 0ULL;
}

// ---------------------------------------------------------------------------
// K2: xg = concat(src,dst) @ W_ih^T + (b_ih + b_hh), fp16 output. (unchanged)
#define GBM 128
#define GBN 128
#define GBK 32
#define LDT 40

__global__ __launch_bounds__(256) void xg_gemm(
    const float* __restrict__ src, const float* __restrict__ dst,
    const float* __restrict__ Wih, const float* __restrict__ bi,
    const float* __restrict__ bh, f16* __restrict__ xg) {
    __shared__ __align__(16) f16 As[GBM * LDT];
    __shared__ __align__(16) f16 Bs[GBN * LDT];

    const int tid = threadIdx.x;
    const int bx  = blockIdx.x;
    const int tm  = bx >> 6, tn = bx & 63;
    const int m0  = tm * GBM, n0 = tn * GBN;
    const int lane = tid & 63, wv = tid >> 6;
    const int wm = (wv >> 1) * 64, wn = (wv & 1) * 64;
    const int fr = lane & 15, kg = lane >> 4;

    const int srow = tid >> 1;
    const int sk   = (tid & 1) * 16;

    f32x4 acc[4][4];
#pragma unroll
    for (int i = 0; i < 4; ++i)
#pragma unroll
        for (int j = 0; j < 4; ++j) acc[i][j] = (f32x4){0.f, 0.f, 0.f, 0.f};

    for (int kt = 0; kt < 2048 / GBK; ++kt) {
        const int gk = kt * GBK + sk;
        {
            const float* ap = (gk < 1024) ? (src + (size_t)(m0 + srow) * 1024 + gk)
                                          : (dst + (size_t)(m0 + srow) * 1024 + (gk - 1024));
            float4 fa = *(const float4*)(ap + 0);
            float4 fb = *(const float4*)(ap + 4);
            float4 fc = *(const float4*)(ap + 8);
            float4 fd = *(const float4*)(ap + 12);
            f16x8 lo, hi;
            lo[0] = (f16)fa.x; lo[1] = (f16)fa.y; lo[2] = (f16)fa.z; lo[3] = (f16)fa.w;
            lo[4] = (f16)fb.x; lo[5] = (f16)fb.y; lo[6] = (f16)fb.z; lo[7] = (f16)fb.w;
            hi[0] = (f16)fc.x; hi[1] = (f16)fc.y; hi[2] = (f16)fc.z; hi[3] = (f16)fc.w;
            hi[4] = (f16)fd.x; hi[5] = (f16)fd.y; hi[6] = (f16)fd.z; hi[7] = (f16)fd.w;
            *(f16x8*)&As[srow * LDT + sk]     = lo;
            *(f16x8*)&As[srow * LDT + sk + 8] = hi;
        }
        {
            const float* bp = Wih + (size_t)(n0 + srow) * 2048 + gk;
            float4 fa = *(const float4*)(bp + 0);
            float4 fb = *(const float4*)(bp + 4);
            float4 fc = *(const float4*)(bp + 8);
            float4 fd = *(const float4*)(bp + 12);
            f16x8 lo, hi;
            lo[0] = (f16)fa.x; lo[1] = (f16)fa.y; lo[2] = (f16)fa.z; lo[3] = (f16)fa.w;
            lo[4] = (f16)fb.x; lo[5] = (f16)fb.y; lo[6] = (f16)fb.z; lo[7] = (f16)fb.w;
            hi[0] = (f16)fc.x; hi[1] = (f16)fc.y; hi[2] = (f16)fc.z; hi[3] = (f16)fc.w;
            hi[4] = (f16)fd.x; hi[5] = (f16)fd.y; hi[6] = (f16)fd.z; hi[7] = (f16)fd.w;
            *(f16x8*)&Bs[srow * LDT + sk]     = lo;
            *(f16x8*)&Bs[srow * LDT + sk + 8] = hi;
        }
        __syncthreads();
        f16x8 a[4], b[4];
#pragma unroll
        for (int m = 0; m < 4; ++m) a[m] = *(const f16x8*)&As[(wm + m * 16 + fr) * LDT + kg * 8];
#pragma unroll
        for (int n = 0; n < 4; ++n) b[n] = *(const f16x8*)&Bs[(wn + n * 16 + fr) * LDT + kg * 8];
#pragma unroll
        for (int m = 0; m < 4; ++m)
#pragma unroll
            for (int n = 0; n < 4; ++n)
                acc[m][n] = __builtin_amdgcn_mfma_f32_16x16x32_f16(a[m], b[n], acc[m][n], 0, 0, 0);
        __syncthreads();
    }
#pragma unroll
    for (int n = 0; n < 4; ++n) {
        const int col = n0 + wn + n * 16 + fr;
        const float bias = bi[col] + bh[col];
#pragma unroll
        for (int m = 0; m < 4; ++m) {
            const int rb = m0 + wm + m * 16 + kg * 4;
#pragma unroll
            for (int r = 0; r < 4; ++r)
                xg[(size_t)(rb + r) * FOURH + col] = (f16)(acc[m][n][r] + bias);
        }
    }
}

// ---------------------------------------------------------------------------
// K3: persistent scan. 256 WGs x 256 threads (4 waves).
// WG w owns m in [8w, 8w+8). Local rows r in [0,32): m = r>>2, g = r&3
// (global W_hh row = g*2048 + 8w + m). K split across waves: wave v owns
// k in [512v, 512v+512) == h-pair entries [256v, 256v+256).
// Lane l of wave v polls entries e = 256v+4l+{0..3} (k = 512v+8l .. +8) and
// holds the matching weights for ALL 32 rows: wreg[32][4] packed f16x2,
// PINNED in VGPRs via asm liveness barrier.
__global__ __launch_bounds__(256, 1) void lstm_scan(
    const float* __restrict__ Whh, const f16* __restrict__ xg,
    unsigned long long* __restrict__ hbuf, float* __restrict__ out) {
    const int w    = blockIdx.x;
    const int tid  = threadIdx.x;
    const int lane = tid & 63;
    const int wv   = tid >> 6;

    __shared__ float scratch[2][4][32][64];   // [slot][wave][row][lane^swz]

    // ---- load + pin weights: 32 rows x 4 f16x2 = 128 VGPRs ----
    const int k0 = 512 * wv + 8 * lane;
    unsigned wreg[32][4];
#pragma unroll
    for (int r = 0; r < 32; ++r) {
        const size_t row = (size_t)((r & 3) * 2048 + w * 8 + (r >> 2));
        const float4* wp = (const float4*)(Whh + row * 2048 + k0);
        float4 a = wp[0], b = wp[1];
        f16x2 p0; p0[0] = (f16)a.x; p0[1] = (f16)a.y;
        f16x2 p1; p1[0] = (f16)a.z; p1[1] = (f16)a.w;
        f16x2 p2; p2[0] = (f16)b.x; p2[1] = (f16)b.y;
        f16x2 p3; p3[0] = (f16)b.z; p3[1] = (f16)b.w;
        wreg[r][0] = __builtin_bit_cast(unsigned, p0);
        wreg[r][1] = __builtin_bit_cast(unsigned, p1);
        wreg[r][2] = __builtin_bit_cast(unsigned, p2);
        wreg[r][3] = __builtin_bit_cast(unsigned, p3);
    }
#pragma unroll
    for (int r = 0; r < 32; ++r)
#pragma unroll
        for (int i = 0; i < 4; ++i)
            asm volatile("" : "+v"(wreg[r][i]));   // pin: no remat, no resink

    unsigned long long* bb0 = hbuf;
    unsigned long long* bb1 = hbuf + 1024;
    const int e0 = 256 * wv + 4 * lane;

    // reduce-phase constants (thread t reduces row rR from quarter vR/half)
    const int q     = tid & 7;
    const int rR    = tid >> 3;            // wave W gets rows [8W, 8W+8)
    const int vR    = q >> 1, halfR = q & 1;
    const int swzR  = ((rR & 7) << 2) ^ (vR << 3);
    const int xcol  = (rR & 3) * 2048 + w * 8 + (rR >> 2);
    const int wswz  = ((0) << 2);          // (unused; write swz computed per row)

    float c_st = 0.f;                      // cell state for m = 2*wv + (lane>=32)

    for (int t = 0; t < T_STEPS; ++t) {
        // xg for the row this thread reduces (only q==0 uses it)
        float xgv = 0.f;
        if (q == 0) xgv = (float)xg[(size_t)t * FOURH + xcol];

        // ---- poll own 4 entries {tag32, f16x2} ----
        unsigned long long* cur = (t & 1) ? bb1 : bb0;
        const unsigned tagw = (unsigned)(t + 1);
        unsigned long long p0, p1, p2, p3;
        for (;;) {
            p0 = __hip_atomic_load(cur + e0 + 0, __ATOMIC_RELAXED, __HIP_MEMORY_SCOPE_AGENT);
            p1 = __hip_atomic_load(cur + e0 + 1, __ATOMIC_RELAXED, __HIP_MEMORY_SCOPE_AGENT);
            p2 = __hip_atomic_load(cur + e0 + 2, __ATOMIC_RELAXED, __HIP_MEMORY_SCOPE_AGENT);
            p3 = __hip_atomic_load(cur + e0 + 3, __ATOMIC_RELAXED, __HIP_MEMORY_SCOPE_AGENT);
            if ((unsigned)(p0 >> 32) >= tagw && (unsigned)(p1 >> 32) >= tagw &&
                (unsigned)(p2 >> 32) >= tagw && (unsigned)(p3 >> 32) >= tagw)
                break;
            __builtin_amdgcn_s_sleep(1);
        }
        f16x2 h0 = __builtin_bit_cast(f16x2, (unsigned)p0);
        f16x2 h1 = __builtin_bit_cast(f16x2, (unsigned)p1);
        f16x2 h2 = __builtin_bit_cast(f16x2, (unsigned)p2);
        f16x2 h3 = __builtin_bit_cast(f16x2, (unsigned)p3);

        // ---- 32 row-partials straight from registers -> swizzled LDS ----
        float* sc = &scratch[t & 1][wv][0][0];
#pragma unroll
        for (int r = 0; r < 32; ++r) {
            float a = FDOT2(__builtin_bit_cast(f16x2, wreg[r][0]), h0, 0.f);
            a = FDOT2(__builtin_bit_cast(f16x2, wreg[r][1]), h1, a);
            a = FDOT2(__builtin_bit_cast(f16x2, wreg[r][2]), h2, a);
            a = FDOT2(__builtin_bit_cast(f16x2, wreg[r][3]), h3, a);
            sc[r * 64 + (lane ^ (((r & 7) << 2) ^ (wv << 3)))] = a;
        }
        __syncthreads();   // the ONE barrier per step

        // ---- final reduce: 8 threads per row ----
        const float* sr = &scratch[t & 1][vR][rR][0];
        float s0 = 0.f;
#pragma unroll
        for (int kk = 0; kk < 8; ++kk) {
            const int idx = ((halfR << 5) + (kk << 2)) ^ swzR;
            f32x4 vv = *(const f32x4*)&sr[idx];
            s0 += vv[0] + vv[1] + vv[2] + vv[3];
        }
        s0 += __shfl_xor(s0, 1);
        s0 += __shfl_xor(s0, 2);
        s0 += __shfl_xor(s0, 4);
        s0 += xgv;                         // valid at q==0 lanes (0,8,...,56)

        // ---- gather 4 gates for this lane's m-half; compute c,h ----
        const int base = lane & 32;        // m' = lane>>5
        float gi = __shfl(s0, base + 0);
        float gf = __shfl(s0, base + 8);
        float gg = __shfl(s0, base + 16);
        float go = __shfl(s0, base + 24);
        float ig = 1.f / (1.f + __expf(-gi));
        float fg = 1.f / (1.f + __expf(-gf));
        float g  = 1.f - 2.f / (__expf(2.f * gg) + 1.f);
        float og = 1.f / (1.f + __expf(-go));
        float c  = fg * c_st + ig * g;
        c_st = c;
        float h = og * (1.f - 2.f / (__expf(2.f * c) + 1.f));

        if (t == T_STEPS - 1) {
            if ((lane & 31) == 0) out[w * 8 + 2 * wv + (lane >> 5)] = h;
        } else {
            float hh = __shfl(h, 32);      // odd-m h
            if (lane == 0) {
                f16x2 hp; hp[0] = (f16)h; hp[1] = (f16)hh;
                unsigned long long val =
                    ((unsigned long long)(unsigned)(t + 2) << 32) |
                    (unsigned long long)__builtin_bit_cast(unsigned, hp);
                unsigned long long* nxt = (t & 1) ? bb0 : bb1;
                __hip_atomic_store(nxt + (w * 4 + wv), val,
                                   __ATOMIC_RELAXED, __HIP_MEMORY_SCOPE_AGENT);
            }
        }
    }
    (void)wswz;
}

// ---------------------------------------------------------------------------
extern "C" void kernel_launch(void* const* d_in, const int* in_sizes, int n_in,
                              void* d_out, int out_size, void* d_ws, size_t ws_size,
                              hipStream_t stream) {
    const float* src = (const float*)d_in[0];
    const float* dst = (const float*)d_in[1];
    const float* Wih = (const float*)d_in[2];
    const float* Whh = (const float*)d_in[3];
    const float* bi  = (const float*)d_in[4];
    const float* bh  = (const float*)d_in[5];
    float* out = (float*)d_out;

    f16* xg = (f16*)d_ws;
    unsigned long long* hbuf =
        (unsigned long long*)((char*)d_ws + ((size_t)64 << 20));

    hipLaunchKernelGGL(init_tags, dim3(8), dim3(256), 0, stream, hbuf);
    hipLaunchKernelGGL(xg_gemm, dim3((4096 / GBM) * (FOURH / GBN)), dim3(256), 0, stream,
                       src, dst, Wih, bi, bh, xg);
    hipLaunchKernelGGL(lstm_scan, dim3(256), dim3(256), 0, stream, Whh, xg, hbuf, out);
}